// Round 1
// 84.502 us; speedup vs baseline: 1.0080x; 1.0080x over previous
//
#include <hip/hip_runtime.h>

// Causal linear attention (elu+1 feature map), chunked-scan formulation.
// Shapes fixed by the reference: N=2, L=2048, H=8, D=64, M=64, fp32.
//
// R12 (from R11 @85.2us): two serialization fixes.
//  (a) k_out: Z = 1/(Q.kpref + rowsum(A) + eps) computed via MFMA with a
//      column-constant B fragment built in registers from wsK (bf16 hi+lo
//      split for fp32-grade precision). Kills the wave0-only 64-iter serial
//      loop, the Rs/Zs LDS arrays, and the third __syncthreads (A-slab
//      write->read is intra-wave: wave w writes and reads only rows
//      16w..16w+15).
//  (b) k_scan: 256 blocks x 128 threads (was 128x256) -> 1 block/CU instead
//      of 0.5, halving the per-CU 32-deep serial prefix chain.

namespace {
constexpr int N_ = 2, L_ = 2048, H_ = 8, D_ = 64, M_ = 64;
constexpr int C  = 64;            // chunk length
constexpr int G  = L_ / C;        // 32 chunks per sequence
constexpr int NH = N_ * H_;       // 16 independent (n,h) sequences
constexpr int LDH = H_ * D_;      // stride (floats) between consecutive l
constexpr int TS  = 72;           // bf16 LDS row stride
constexpr float EPS_ = 1e-6f;
}

typedef __attribute__((ext_vector_type(8))) short short8;
typedef __attribute__((ext_vector_type(4))) float f32x4;

__device__ __forceinline__ float phi(float x) {
    return x > 0.0f ? x + 1.0f : __expf(x);
}
__device__ __forceinline__ unsigned short f2bf(float x) {
    unsigned int u = __float_as_uint(x);
    u += 0x7fffu + ((u >> 16) & 1u);          // round-to-nearest-even
    return (unsigned short)(u >> 16);
}
__device__ __forceinline__ float bf2f(unsigned short h) {
    return __uint_as_float(((unsigned int)h) << 16);
}
__device__ __forceinline__ ushort4 pack4(float a, float b, float c, float d) {
    ushort4 p; p.x = f2bf(a); p.y = f2bf(b); p.z = f2bf(c); p.w = f2bf(d);
    return p;
}

// ---------------------------------------------------------------------------
// Kernel 1 (MFMA): S_chunk^T[m][d] (bf16, packed) and ksum[d] (fp32)
// ---------------------------------------------------------------------------
__global__ __launch_bounds__(256, 4) void k_chunksum(
    const float* __restrict__ keys, const float* __restrict__ values,
    unsigned short* __restrict__ wsSb, float* __restrict__ wsK)
{
    __shared__ __align__(16) unsigned short Kt[C * TS];
    __shared__ __align__(16) unsigned short Vt[C * TS];
    const int bid = blockIdx.x;
    const int g = bid % G, nh = bid / G;
    const int n = nh / H_, h = nh % H_;
    const int t = threadIdx.x;
    const size_t base = ((size_t)(n * L_ + g * C) * H_ + h) * D_;

    // stage with transpose scatter: Kt[d][j] = phi(K)^T, Vt[m][j] = V^T
#pragma unroll
    for (int r = 0; r < 4; ++r) {
        const int f = t + 256 * r;
        const int j = f >> 4, c = (f & 15) * 4;
        const size_t ga = base + (size_t)j * LDH + c;
        const float4 kv = *(const float4*)(keys + ga);
        const float4 vv = *(const float4*)(values + ga);
        Kt[(c + 0) * TS + j] = f2bf(phi(kv.x));
        Kt[(c + 1) * TS + j] = f2bf(phi(kv.y));
        Kt[(c + 2) * TS + j] = f2bf(phi(kv.z));
        Kt[(c + 3) * TS + j] = f2bf(phi(kv.w));
        Vt[(c + 0) * TS + j] = f2bf(vv.x);
        Vt[(c + 1) * TS + j] = f2bf(vv.y);
        Vt[(c + 2) * TS + j] = f2bf(vv.z);
        Vt[(c + 3) * TS + j] = f2bf(vv.w);
    }
    __syncthreads();

    const int w = t >> 6, lane = t & 63;
    const int row16 = lane & 15, quad = lane >> 4;

    f32x4 acc[4] = {f32x4{0,0,0,0}, f32x4{0,0,0,0}, f32x4{0,0,0,0}, f32x4{0,0,0,0}};
    f32x4 accK = f32x4{0,0,0,0};
    short8 ones;
#pragma unroll
    for (int i = 0; i < 8; ++i) ones[i] = (short)0x3F80;   // bf16(1.0)

#pragma unroll
    for (int kt = 0; kt < 2; ++kt) {
        const short8 a = *(const short8*)&Kt[(16 * w + row16) * TS + quad * 8 + 32 * kt];
#pragma unroll
        for (int c = 0; c < 4; ++c) {
            const short8 b = *(const short8*)&Vt[(16 * c + row16) * TS + quad * 8 + 32 * kt];
            acc[c] = __builtin_amdgcn_mfma_f32_16x16x32_bf16(a, b, acc[c], 0, 0, 0);
        }
        accK = __builtin_amdgcn_mfma_f32_16x16x32_bf16(a, ones, accK, 0, 0, 0);
    }

    // store transposed: S^T[m][d], d-run of 4 packed into one 8B write
    unsigned short* Sc = wsSb + (size_t)bid * (D_ * M_);
#pragma unroll
    for (int c = 0; c < 4; ++c) {
        *(ushort4*)(Sc + (16 * c + row16) * D_ + 16 * w + quad * 4) =
            pack4(acc[c][0], acc[c][1], acc[c][2], acc[c][3]);
    }

    if (row16 == 0) {
#pragma unroll
        for (int r = 0; r < 4; ++r)
            wsK[(size_t)bid * D_ + 16 * w + quad * 4 + r] = accK[r];
    }
}

// ---------------------------------------------------------------------------
// Kernel 2: exclusive prefix scan over chunks.
// S: bf16, 2 chains packed per uint per thread (fp32 running sums).
// ksum: fp32, one float per thread (blocks with q==0).
// 256 blocks x 128 threads: one block per CU (was 128x256 = half the CUs).
// ---------------------------------------------------------------------------
__global__ __launch_bounds__(128) void k_scan(
    unsigned short* __restrict__ wsSb, float* __restrict__ wsK)
{
    const int bid = blockIdx.x;               // 256 blocks
    const int nh = bid >> 4, q = bid & 15;    // 16 blocks per nh
    const int t = threadIdx.x;                // 0..127

    unsigned int* base =
        (unsigned int*)(wsSb + (size_t)nh * G * (D_ * M_) + q * 256 + t * 2);
    float r0 = 0.f, r1 = 0.f;
#pragma unroll
    for (int g = 0; g < G; ++g) {
        unsigned int* p = base + (size_t)g * (D_ * M_ / 2);
        const unsigned int v = *p;
        const float v0 = bf2f((unsigned short)(v & 0xffffu));
        const float v1 = bf2f((unsigned short)(v >> 16));
        *p = ((unsigned int)f2bf(r1) << 16) | (unsigned int)f2bf(r0);
        r0 += v0; r1 += v1;
    }

    if (q == 0 && t < D_) {
        float rk = 0.f;
        float* kb = wsK + (size_t)nh * G * D_ + t;
#pragma unroll
        for (int g = 0; g < G; ++g) {
            float* p = kb + (size_t)g * D_;
            const float v = *p;
            *p = rk;
            rk += v;
        }
    }
}

// ---------------------------------------------------------------------------
// Kernel 3 (MFMA): A = tril(phiQ phiK^T); Z = 1/(phiQ.kp + rowsum(A) + eps);
// out = (A @ V + phiQ @ Sp) * Z.
// Z computed via MFMA with a column-constant B fragment (kpref, bf16 hi+lo
// split) -> no serial wave0 section, no Rs/Zs LDS, only two barriers.
// ---------------------------------------------------------------------------
__global__ __launch_bounds__(256, 4) void k_out(
    const float* __restrict__ queries, const float* __restrict__ keys,
    const float* __restrict__ values, float* __restrict__ out,
    const unsigned short* __restrict__ wsSb, const float* __restrict__ wsK)
{
    __shared__ __align__(16) unsigned short Qb[C * TS];
    __shared__ __align__(16) unsigned short Kb[C * TS];   // phi(K) -> A
    __shared__ __align__(16) unsigned short Vt[C * TS];
    __shared__ __align__(16) unsigned short St[C * TS];

    const int bid = blockIdx.x;
    const int g = bid % G, nh = bid / G;
    const int n = nh / H_, h = nh % H_;
    const int t = threadIdx.x;
    const size_t base = ((size_t)(n * L_ + g * C) * H_ + h) * D_;
    const unsigned short* Spb = wsSb + (size_t)bid * (D_ * M_);
    const float* kpref = wsK + (size_t)bid * D_;

    // ---- stage: Qb/Kb contiguous (packed stores), Vt transposed -----------
#pragma unroll
    for (int r = 0; r < 4; ++r) {
        const int f = t + 256 * r;
        const int row = f >> 4, c = (f & 15) * 4;
        const size_t ga = base + (size_t)row * LDH + c;
        const float4 qv = *(const float4*)(queries + ga);
        const float4 kv = *(const float4*)(keys + ga);
        const float4 vv = *(const float4*)(values + ga);
        *(ushort4*)&Qb[row * TS + c] = pack4(phi(qv.x), phi(qv.y), phi(qv.z), phi(qv.w));
        *(ushort4*)&Kb[row * TS + c] = pack4(phi(kv.x), phi(kv.y), phi(kv.z), phi(kv.w));
        Vt[(c + 0) * TS + row] = f2bf(vv.x);
        Vt[(c + 1) * TS + row] = f2bf(vv.y);
        Vt[(c + 2) * TS + row] = f2bf(vv.z);
        Vt[(c + 3) * TS + row] = f2bf(vv.w);
    }
    // St^T: straight bf16 copy (already transposed in ws)
#pragma unroll
    for (int r = 0; r < 2; ++r) {
        const int idx = t + 256 * r;              // 0..511
        const int m = idx >> 3, dg = (idx & 7) * 8;
        *(short8*)&St[m * TS + dg] = *(const short8*)(Spb + m * D_ + dg);
    }

    const int w = t >> 6, lane = t & 63;
    const int row16 = lane & 15, quad = lane >> 4;

    // ---- kpref B-fragments (column-constant): B[k][*] = kpref[k] ----------
    // fragment element i of kt-th tile is kpref[32*kt + quad*8 + i];
    // hi+lo bf16 split keeps fp32-grade precision through the bf16 MFMA.
    const float* kp0 = kpref + quad * 8;
    const float4 kfa = *(const float4*)(kp0);
    const float4 kfb = *(const float4*)(kp0 + 4);
    const float4 kfc = *(const float4*)(kp0 + 32);
    const float4 kfd = *(const float4*)(kp0 + 36);
    short8 bZhi0, bZhi1, bZlo0, bZlo1;
    {
        const float f0[8] = {kfa.x, kfa.y, kfa.z, kfa.w, kfb.x, kfb.y, kfb.z, kfb.w};
        const float f1[8] = {kfc.x, kfc.y, kfc.z, kfc.w, kfd.x, kfd.y, kfd.z, kfd.w};
#pragma unroll
        for (int i = 0; i < 8; ++i) {
            const unsigned short h0 = f2bf(f0[i]);
            bZhi0[i] = (short)h0;
            bZlo0[i] = (short)f2bf(f0[i] - bf2f(h0));
            const unsigned short h1 = f2bf(f1[i]);
            bZhi1[i] = (short)h1;
            bZlo1[i] = (short)f2bf(f1[i] - bf2f(h1));
        }
    }
    __syncthreads();

    // ---- QK^T: wave w -> rows 16w..16w+15, all 4 col-tiles ----------------
    short8 aq[2];
#pragma unroll
    for (int kt = 0; kt < 2; ++kt)
        aq[kt] = *(const short8*)&Qb[(16 * w + row16) * TS + quad * 8 + 32 * kt];

    f32x4 accA[4] = {f32x4{0,0,0,0}, f32x4{0,0,0,0}, f32x4{0,0,0,0}, f32x4{0,0,0,0}};
#pragma unroll
    for (int kt = 0; kt < 2; ++kt)
#pragma unroll
        for (int c = 0; c < 4; ++c) {
            const short8 b = *(const short8*)&Kb[(16 * c + row16) * TS + quad * 8 + 32 * kt];
            accA[c] = __builtin_amdgcn_mfma_f32_16x16x32_bf16(aq[kt], b, accA[c], 0, 0, 0);
        }

    // ---- Z numerator part: accZ[r] = phiQ(row).kpref, all lanes -----------
    f32x4 accZ = f32x4{0, 0, 0, 0};
    accZ = __builtin_amdgcn_mfma_f32_16x16x32_bf16(aq[0], bZhi0, accZ, 0, 0, 0);
    accZ = __builtin_amdgcn_mfma_f32_16x16x32_bf16(aq[1], bZhi1, accZ, 0, 0, 0);
    accZ = __builtin_amdgcn_mfma_f32_16x16x32_bf16(aq[0], bZlo0, accZ, 0, 0, 0);
    accZ = __builtin_amdgcn_mfma_f32_16x16x32_bf16(aq[1], bZlo1, accZ, 0, 0, 0);

    // ---- mask (causal) in fp32 + in-register rowsums ----------------------
    float rs[4] = {0.f, 0.f, 0.f, 0.f};
#pragma unroll
    for (int c = 0; c < 4; ++c)
#pragma unroll
        for (int r = 0; r < 4; ++r) {
            const int row = 16 * w + quad * 4 + r;
            const int col = 16 * c + row16;
            const float v = (col <= row) ? accA[c][r] : 0.f;
            accA[c][r] = v;
            rs[r] += v;
        }
#pragma unroll
    for (int off = 1; off < 16; off <<= 1)
#pragma unroll
        for (int r = 0; r < 4; ++r)
            rs[r] += __shfl_xor(rs[r], off, 64);
    // rs[r] now = full rowsum of row 16w+quad*4+r, held by every lane that
    // will scale that row's outputs. No LDS round-trip needed.

    __syncthreads();   // all Kb reads (QK^T) done before overwrite with A

    // ---- write A (bf16) into Kb slab --------------------------------------
    // wave w writes rows 16w..16w+15 and below reads back only those rows:
    // intra-wave LDS ordering, no block barrier required.
#pragma unroll
    for (int c = 0; c < 4; ++c)
#pragma unroll
        for (int r = 0; r < 4; ++r)
            Kb[(16 * w + quad * 4 + r) * TS + 16 * c + row16] = f2bf(accA[c][r]);

    // ---- out = (A @ V + Q @ Sp) * Z ---------------------------------------
    f32x4 accO[4] = {f32x4{0,0,0,0}, f32x4{0,0,0,0}, f32x4{0,0,0,0}, f32x4{0,0,0,0}};
#pragma unroll
    for (int kt = 0; kt < 2; ++kt) {
        const short8 aA = *(const short8*)&Kb[(16 * w + row16) * TS + quad * 8 + 32 * kt];
#pragma unroll
        for (int c = 0; c < 4; ++c) {
            const short8 bV = *(const short8*)&Vt[(16 * c + row16) * TS + quad * 8 + 32 * kt];
            accO[c] = __builtin_amdgcn_mfma_f32_16x16x32_bf16(aA, bV, accO[c], 0, 0, 0);
        }
#pragma unroll
        for (int c = 0; c < 4; ++c) {
            const short8 bS = *(const short8*)&St[(16 * c + row16) * TS + quad * 8 + 32 * kt];
            accO[c] = __builtin_amdgcn_mfma_f32_16x16x32_bf16(aq[kt], bS, accO[c], 0, 0, 0);
        }
    }

#pragma unroll
    for (int r = 0; r < 4; ++r) {
        const int row = 16 * w + quad * 4 + r;
        const float z = 1.0f / (accZ[r] + rs[r] + EPS_);
        const size_t ob = ((size_t)(n * L_ + g * C + row) * H_ + h) * M_;
#pragma unroll
        for (int c = 0; c < 4; ++c)
            out[ob + 16 * c + row16] = accO[c][r] * z;
    }
}

extern "C" void kernel_launch(void* const* d_in, const int* in_sizes, int n_in,
                              void* d_out, int out_size, void* d_ws, size_t ws_size,
                              hipStream_t stream) {
    const float* q = (const float*)d_in[0];
    const float* k = (const float*)d_in[1];
    const float* v = (const float*)d_in[2];
    float* out = (float*)d_out;
    unsigned short* wsSb = (unsigned short*)d_ws;            // NH*G*D*M bf16 (4 MB)
    float* wsK = (float*)((char*)d_ws + (size_t)NH * G * D_ * M_ * 2);  // fp32 128 KB

    k_chunksum<<<dim3(NH * G), dim3(256), 0, stream>>>(k, v, wsSb, wsK);
    k_scan<<<dim3(NH * 16), dim3(128), 0, stream>>>(wsSb, wsK);
    k_out<<<dim3(NH * G), dim3(256), 0, stream>>>(q, k, v, out, wsSb, wsK);
}